// Round 14
// baseline (61.771 us; speedup 1.0000x reference)
//
#include <hip/hip_runtime.h>

#define NQ 12
#define NLAYERS 4

typedef float v2f __attribute__((ext_vector_type(2)));
typedef unsigned uint2v __attribute__((ext_vector_type(2)));

// ---- DPP move: value from another lane, compile-time ctrl ----
template<int CTRL>
__device__ __forceinline__ float dppmov(float v) {
    return __uint_as_float((unsigned)__builtin_amdgcn_update_dpp(
        0, (int)__float_as_uint(v), CTRL, 0xF, 0xF, true));
}

// ---- value from lane ^ (1<<LB); all 64 lanes active; NO DS-pipe ops ----
// DPP row_ror:n semantics: lane i reads lane (i-n) mod 16.
template<int LB>
__device__ __forceinline__ float lx(float v, int lane) {
    if constexpr (LB == 0) {
        return dppmov<0xB1>(v);                 // quad_perm [1,0,3,2] = xor1
    } else if constexpr (LB == 1) {
        return dppmov<0x4E>(v);                 // quad_perm [2,3,0,1] = xor2
    } else if constexpr (LB == 2) {
        float a = dppmov<0x124>(v);             // row_ror:4  -> reads (i-4)%16
        float b = dppmov<0x12C>(v);             // row_ror:12 -> reads (i+4)%16
        return (lane & 4) ? a : b;
    } else if constexpr (LB == 3) {
        return dppmov<0x128>(v);                // row_ror:8 = xor8
    } else if constexpr (LB == 4) {
#if __has_builtin(__builtin_amdgcn_permlane16_swap)
        uint2v r = __builtin_amdgcn_permlane16_swap(__float_as_uint(v), __float_as_uint(v), false, false);
        return __uint_as_float(r.x) + __uint_as_float(r.y) - v;   // partner
#else
        return __shfl_xor(v, 16, 64);
#endif
    } else {
#if __has_builtin(__builtin_amdgcn_permlane32_swap)
        uint2v r = __builtin_amdgcn_permlane32_swap(__float_as_uint(v), __float_as_uint(v), false, false);
        return __uint_as_float(r.x) + __uint_as_float(r.y) - v;
#else
        return __shfl_xor(v, 32, 64);
#endif
    }
}

template<int LB>
__device__ __forceinline__ v2f lxv(v2f a, int lane) {
    v2f r;
    r.x = lx<LB>(a.x, lane);
    r.y = lx<LB>(a.y, lane);
    return r;
}

// ======== composed ring permutation: source index for CNOT ring (i,(i+S)%12) ========
template<int S>
__host__ __device__ constexpr int ringsrc_c(int k) {
    int s = k;
    for (int i = 11; i >= 0; --i) {
        const int pc = 11 - i;
        const int pt = 11 - ((i + S) % 12);
        s ^= ((s >> pc) & 1) << pt;
    }
    return s;
}

__host__ __device__ constexpr int ror1_4(int m) {
    return ((m >> 1) | ((m & 1) << 3)) & 15;
}
// LDS swizzle (GF(2)-linear): phys(s) = s ^ ror1(mid4). Rank-4 lane-spread for
// write AND ring-S reads, S=1..4 (verified R10: conflicts at b64 floor).
__host__ __device__ constexpr int phys_lin(int s) {
    return s ^ ror1_4((s >> 4) & 15);
}

struct LUT16 { int v[16]; };

template<int S>
__host__ __device__ constexpr LUT16 make_lr() {
    LUT16 a{};
    for (int r = 0; r < 16; ++r) a.v[r] = ringsrc_c<S>(r);
    return a;
}
template<int S>
__host__ __device__ constexpr LUT16 make_pr() {
    LUT16 a{};
    for (int r = 0; r < 16; ++r) a.v[r] = phys_lin(ringsrc_c<S>(r));
    return a;
}
template<int S>
__host__ __device__ constexpr bool grp_used(int h) {
    for (int r = 0; r < 16; ++r)
        if (((ringsrc_c<S>(r) >> 10) & 3) == h) return true;
    return false;
}

// ================= real RY gates (Rot = RZ(om)·RY(th)·RZ(phi) decomposition) =================
template<int RB>
__device__ __forceinline__ void ry_reg(v2f (&st)[16], float c, float s) {
    #pragma unroll
    for (int r = 0; r < 16; ++r) if (!(r & (1 << RB))) {
        const int r1 = r | (1 << RB);
        v2f a0 = st[r], a1 = st[r1];
        st[r]  = c * a0 - s * a1;
        st[r1] = s * a0 + c * a1;
    }
}
template<int LB>
__device__ __forceinline__ void ry_lane(v2f (&st)[16], int lane, float c, float s) {
    const float so = ((lane >> LB) & 1) ? s : -s;
    #pragma unroll
    for (int r = 0; r < 16; ++r) {
        v2f oth = lxv<LB>(st[r], lane);
        st[r] = c * st[r] + so * oth;
    }
}

// ================= diagonal apply: st[r] *= e^{i(A + sum_{bits b of r} angle_b)} ===========
// f = 4 (cos,sin) pairs, f[b] = e^{i*angle_{wire 11-b}} (full angle)
__device__ __forceinline__ void diag_apply(v2f (&st)[16], float A, const float* __restrict__ f) {
    float sA, cA;
    __sincosf(A, &sA, &cA);
    v2f p[16];
    p[0] = v2f{cA, sA};
    #pragma unroll
    for (int r = 1; r < 16; ++r) {
        const int b = (r & 1) ? 0 : ((r & 2) ? 1 : ((r & 4) ? 2 : 3));
        const v2f q = p[r & (r - 1)];
        const float fc = f[2 * b], fs = f[2 * b + 1];
        p[r] = v2f{fc * q.x - fs * q.y, fc * q.y + fs * q.x};
    }
    #pragma unroll
    for (int r = 0; r < 16; ++r) {
        const v2f a = st[r], q = p[r];
        st[r] = v2f{a.x * q.x - a.y * q.y, a.x * q.y + a.y * q.x};
    }
}

// ================= fused trip: RY(w0)⊗RY(w1) [+row phase] + ring-S =================
__device__ __forceinline__ void trip_write(const v2f (&st)[16], int wbase, int lsw, v2f* buf) {
    #pragma unroll
    for (int r = 0; r < 16; ++r) buf[wbase | (r ^ lsw)] = st[r];
}

template<int S, int H, bool RP>
__device__ __forceinline__ void trip_group(v2f (&st)[16], int pb, int rowbase,
                                           const v2f* buf, const float* __restrict__ P) {
    if constexpr (grp_used<S>(H)) {
        const int row = rowbase ^ H;
        const float rm0 = P[66 + row * 4 + 0], rm1 = P[66 + row * 4 + 1],
                    rm2 = P[66 + row * 4 + 2], rm3 = P[66 + row * 4 + 3];
        float pc = 0.f, ps = 0.f;
        if constexpr (RP) { pc = P[82 + 2 * row]; ps = P[83 + 2 * row]; }
        constexpr LUT16 LR = make_lr<S>();
        constexpr LUT16 PR = make_pr<S>();
        #pragma unroll
        for (int r = 0; r < 16; ++r) {
            if (((LR.v[r] >> 10) & 3) == H) {
                const int a = (pb ^ PR.v[r]) & 1023;
                v2f acc = rm0 * buf[a]
                        + rm1 * buf[a + 1024]
                        + rm2 * buf[a + 2048]
                        + rm3 * buf[a + 3072];
                if constexpr (RP)
                    st[r] = v2f{acc.x * pc - acc.y * ps, acc.y * pc + acc.x * ps};
                else
                    st[r] = acc;
            }
        }
    }
}

template<int S, bool RP>
__device__ __forceinline__ void trip_read(v2f (&st)[16], int wbase,
                                          const v2f* buf, const float* __restrict__ P) {
    const int sb = ringsrc_c<S>(wbase);
    const int pb = phys_lin(sb);
    const int rowbase = (sb >> 10) & 3;
    trip_group<S, 0, RP>(st, pb, rowbase, buf, P);
    trip_group<S, 1, RP>(st, pb, rowbase, buf, P);
    trip_group<S, 2, RP>(st, pb, rowbase, buf, P);
    trip_group<S, 3, RP>(st, pb, rowbase, buf, P);
}

// ================= one layer: D_phi -> 10 real RY -> [D_omega(2..11)] -> trip =============
// Per-layer param block P (128 floats):
// [0..11] c_w  [12..23] s_w  [24..35] phi_w/2  [36..47] om_w/2
// [48..55] fphi[b]=(cos,sin)(phi_{11-b})  [56..63] fom[b]=(cos,sin)(om_{11-b})
// [64] -sum(phi_w/2)  [65] -sum_{w>=2}(om_w/2)
// [66..81] m4r[i][j]  [82..89] rowphase[i]=(cos,sin)(beta_i)
template<int S, bool FULL>
__device__ __forceinline__ void do_layer(v2f (&st)[16], int lane, int wv, int wbase, int lsw,
                                         v2f* xch, const float* __restrict__ P) {
    {   // D_phi (all 12 wires): base over wave+lane bits, table over reg bits
        float A = P[64];
        A += ((wv >> 1) & 1) ? 2.f * P[24 + 0] : 0.f;
        A += (wv & 1)        ? 2.f * P[24 + 1] : 0.f;
        #pragma unroll
        for (int w = 2; w < 8; ++w)
            A += ((lane >> (7 - w)) & 1) ? 2.f * P[24 + w] : 0.f;
        diag_apply(st, A, P + 48);
    }
    ry_lane<5>(st, lane, P[2],  P[14]);   // wire 2
    ry_lane<4>(st, lane, P[3],  P[15]);   // wire 3
    ry_lane<3>(st, lane, P[4],  P[16]);   // wire 4
    ry_lane<2>(st, lane, P[5],  P[17]);   // wire 5
    ry_lane<1>(st, lane, P[6],  P[18]);   // wire 6
    ry_lane<0>(st, lane, P[7],  P[19]);   // wire 7
    ry_reg<3>(st, P[8],  P[20]);          // wire 8
    ry_reg<2>(st, P[9],  P[21]);          // wire 9
    ry_reg<1>(st, P[10], P[22]);          // wire 10
    ry_reg<0>(st, P[11], P[23]);          // wire 11
    if constexpr (FULL) {   // D_omega wires 2..11 (commutes with trip's RY0,RY1)
        float A = P[65];
        #pragma unroll
        for (int w = 2; w < 8; ++w)
            A += ((lane >> (7 - w)) & 1) ? 2.f * P[36 + w] : 0.f;
        diag_apply(st, A, P + 56);
    }
    trip_write(st, wbase, lsw, xch);
    __syncthreads();
    trip_read<S, FULL>(st, wbase, xch, P);   // D_omega(0,1) folded into row phases
    __syncthreads();
}

// ================= param precompute (batch-independent) =================
__global__ void prep_mats(const float* __restrict__ w3, float* __restrict__ prm) {
    int t = threadIdx.x;
    if (t < NLAYERS * NQ) {
        int l = t / 12, w = t % 12;
        float phi = w3[t * 3 + 0], th = w3[t * 3 + 1], om = w3[t * 3 + 2];
        float* P = prm + l * 128;
        P[w]      = cosf(0.5f * th);
        P[12 + w] = sinf(0.5f * th);
        P[24 + w] = 0.5f * phi;
        P[36 + w] = 0.5f * om;
    }
    if (t < NLAYERS) {
        const int l = t;
        const float* W = w3 + l * 36;
        float* P = prm + l * 128;
        float nphi = 0.f, nomg = 0.f;
        for (int w = 0; w < 12; ++w) nphi -= 0.5f * W[w * 3 + 0];
        for (int w = 2; w < 12; ++w) nomg -= 0.5f * W[w * 3 + 2];
        P[64] = nphi;
        P[65] = nomg;
        for (int b = 0; b < 4; ++b) {
            int w = 11 - b;
            P[48 + 2 * b] = cosf(W[w * 3 + 0]);  P[49 + 2 * b] = sinf(W[w * 3 + 0]);
            P[56 + 2 * b] = cosf(W[w * 3 + 2]);  P[57 + 2 * b] = sinf(W[w * 3 + 2]);
        }
        float c0 = cosf(0.5f * W[0 * 3 + 1]), s0 = sinf(0.5f * W[0 * 3 + 1]);
        float c1 = cosf(0.5f * W[1 * 3 + 1]), s1 = sinf(0.5f * W[1 * 3 + 1]);
        float R0[2][2] = {{c0, -s0}, {s0, c0}};
        float R1[2][2] = {{c1, -s1}, {s1, c1}};
        float ho0 = 0.5f * W[0 * 3 + 2], ho1 = 0.5f * W[1 * 3 + 2];
        for (int i = 0; i < 4; ++i) {
            for (int j = 0; j < 4; ++j)
                P[66 + i * 4 + j] = R0[i >> 1][j >> 1] * R1[i & 1][j & 1];
            float beta = (2 * (i >> 1) - 1) * ho0 + (2 * (i & 1) - 1) * ho1;
            P[82 + 2 * i] = cosf(beta);
            P[83 + 2 * i] = sinf(beta);
        }
    }
}

__device__ __forceinline__ float wsum(float v, int lane) {
    v += lx<5>(v, lane); v += lx<4>(v, lane); v += lx<3>(v, lane);
    v += lx<2>(v, lane); v += lx<1>(v, lane); v += lx<0>(v, lane);
    return v;
}

// ================= main kernel =================
__global__ __launch_bounds__(256)
__attribute__((amdgpu_waves_per_eu(2)))
void qsim_kernel(
    const float* __restrict__ x,       // [B][NQ]
    const float* __restrict__ prm,     // 4 x 128 floats
    float* __restrict__ out)           // [B][NQ]
{
    __shared__ v2f xch[4096];          // 32 KB (phys-swizzled state exchange)

    const int b     = blockIdx.x;
    const int tid   = threadIdx.x;
    const int wv    = tid >> 6;
    const int lane  = tid & 63;
    const int wbase = (wv << 10) | (lane << 4);
    const int lsw   = ror1_4(lane & 15);

    const float PI = 3.14159265358979323846f;

    // ---- RY product state WITH initial ring1 folded in (zero LDS) ----
    float cs[12], sn[12];
    #pragma unroll
    for (int w = 0; w < 12; ++w) {
        float h = 0.5f * PI * x[b * NQ + w];
        __sincosf(h, &sn[w], &cs[w]);
    }
    const int sbi = ringsrc_c<1>(wbase);
    float LF = 1.f;
    #pragma unroll
    for (int w = 2; w < 8; ++w)
        LF *= ((sbi >> (11 - w)) & 1) ? sn[w] : cs[w];
    constexpr LUT16 L1R = make_lr<1>();
    v2f st[16];
    #pragma unroll
    for (int r = 0; r < 16; ++r) {
        const int idx = sbi ^ L1R.v[r];
        float f = LF;
        f *= ((idx >> 11) & 1) ? sn[0]  : cs[0];
        f *= ((idx >> 10) & 1) ? sn[1]  : cs[1];
        f *= ((idx >> 3) & 1)  ? sn[8]  : cs[8];
        f *= ((idx >> 2) & 1)  ? sn[9]  : cs[9];
        f *= ((idx >> 1) & 1)  ? sn[10] : cs[10];
        f *= ( idx       & 1)  ? sn[11] : cs[11];
        st[r] = v2f{f, 0.f};
    }

    // ---- 4 entangling layers (last layer: drop |.|^2-invariant phases) ----
    do_layer<1, true >(st, lane, wv, wbase, lsw, xch, prm + 0);
    do_layer<2, true >(st, lane, wv, wbase, lsw, xch, prm + 128);
    do_layer<3, true >(st, lane, wv, wbase, lsw, xch, prm + 256);
    do_layer<4, false>(st, lane, wv, wbase, lsw, xch, prm + 384);

    // ---- per-wire <Z> ----
    float S = 0.f;
    float aR[4] = {0.f, 0.f, 0.f, 0.f};
    #pragma unroll
    for (int r = 0; r < 16; ++r) {
        v2f sq = st[r] * st[r];
        float pr = sq.x + sq.y;
        S += pr;
        #pragma unroll
        for (int rb = 0; rb < 4; ++rb)
            aR[rb] += ((r >> rb) & 1) ? -pr : pr;
    }

    float* red = (float*)xch;

    {   // wave wires 0,1
        float T = wsum(S, lane);
        if (lane == 0) {
            red[wv * 12 + 0] = ((wv >> 1) & 1) ? -T : T;
            red[wv * 12 + 1] = (wv & 1) ? -T : T;
        }
    }
    #pragma unroll
    for (int W = 2; W < 8; ++W) {      // lane wires
        float v0 = ((lane >> (7 - W)) & 1) ? -S : S;
        v0 = wsum(v0, lane);
        if (lane == 0) red[wv * 12 + W] = v0;
    }
    #pragma unroll
    for (int W = 8; W < 12; ++W) {     // reg wires
        float v0 = wsum(aR[11 - W], lane);
        if (lane == 0) red[wv * 12 + W] = v0;
    }
    __syncthreads();
    if (tid < 12)
        out[b * NQ + tid] = red[tid] + red[12 + tid] + red[24 + tid] + red[36 + tid];
}

extern "C" void kernel_launch(void* const* d_in, const int* in_sizes, int n_in,
                              void* d_out, int out_size, void* d_ws, size_t ws_size,
                              hipStream_t stream) {
    const float* x  = (const float*)d_in[0];   // [B][NQ] float32
    const float* w3 = (const float*)d_in[1];   // [NLAYERS][NQ][3] float32
    float* out = (float*)d_out;                // [B][NQ] float32
    float* prm = (float*)d_ws;                 // 4*128 floats = 2 KB
    int batch = in_sizes[0] / NQ;
    prep_mats<<<1, 64, 0, stream>>>(w3, prm);
    qsim_kernel<<<batch, 256, 0, stream>>>(x, prm, out);
}